// Round 7
// baseline (568.011 us; speedup 1.0000x reference)
//
#include <hip/hip_runtime.h>
#include <stdint.h>

typedef unsigned int u32;
typedef unsigned long long u64;

#define BB 8
#define NN 8192
#define CC 80
#define KK 1000
#define NC (NN*CC)            // 655360
#define MAXIDX (NC-1)
#define NMS_THR 0.5f
#define SCORE_THR 0.05f
#define MAX_RATIO 4.135166556742356f
#define CLS_OFF 10000.0f
#define CAP 2048
#define NW 16                 // u64 words per mask row
#define GB 128                // blocks per batch
#define NBLK (GB*BB)          // 1024 persistent blocks
#define NTILE 136             // lower-triangle 16x16 tile pairs

// ---- workspace layout (bytes) ----
#define WS_HIST1   0          // 8*2048*4 = 65536
#define WS_HIST2   65536      // 65536
#define WS_GCOUNT  131072     // 32
#define WS_BAR     131104     // 8*4 = 32
#define WS_CTRL_END 131136    // zeroed by init_ws (= 16*8196)
#define WS_GBUF    131136     // B*CAP*8 = 131072 -> 262208
#define WS_TBOX    262208     // 128000
#define WS_TOBOX   390208     // 128000
#define WS_TSCORE  518208     // 32000
#define WS_TCLS    550208     // 32000
#define WS_TVALID  582208     // 32000
#define WS_MASK    614208     // B*NW*KK*8 = 1024000 -> ends 1638208

__device__ __forceinline__ u32 mapf(float f) {
    u32 u = __float_as_uint(f);
    return (u & 0x80000000u) ? ~u : (u | 0x80000000u);
}
__device__ __forceinline__ float unmapf(u32 m) {
    u32 u = (m & 0x80000000u) ? (m ^ 0x80000000u) : ~m;
    return __uint_as_float(u);
}

// ---------------- init: zero control region (hists + gcount + barrier counters) --------
__global__ __launch_bounds__(256) void init_ws(uint4* __restrict__ p) {
    int i = blockIdx.x * blockDim.x + threadIdx.x;
    if (i < (WS_CTRL_END / 16)) p[i] = make_uint4(0u, 0u, 0u, 0u);
}

// software grid barrier: all NBLK blocks resident (enforced by __launch_bounds__(256,4))
__device__ __forceinline__ void gbar(u32* bar, int k) {
    __syncthreads();
    if (threadIdx.x == 0) {
        __threadfence();                         // release (device scope: L2 wb)
        atomicAdd(&bar[k], 1u);
        while (__hip_atomic_load(&bar[k], __ATOMIC_RELAXED, __HIP_MEMORY_SCOPE_AGENT) < (u32)NBLK)
            __builtin_amdgcn_s_sleep(2);
        __threadfence();                         // acquire (device scope: inv)
    }
    __syncthreads();
}

// digit-select from a finalized 2048-bin global histogram (descending). blockDim=256.
// bc[0]=digit, bc[1]=remaining need inside that digit.
__device__ __forceinline__ void sel_digit(const u32* __restrict__ h, u32 need,
                                          u32* suf, u32* bc) {
    int t = threadIdx.x;
    u32 hv[8];
    u32 s = 0;
    #pragma unroll
    for (int q = 0; q < 8; ++q) { hv[q] = h[t * 8 + q]; s += hv[q]; }
    u32 grp = s;
    suf[t] = s;
    __syncthreads();
    #pragma unroll
    for (int off = 1; off < 256; off <<= 1) {
        u32 v = (t + off < 256) ? suf[t + off] : 0u;
        __syncthreads();
        suf[t] += v;
        __syncthreads();
    }
    u32 cumAbove = suf[t] - grp;
    if (cumAbove < need && suf[t] >= need) {     // unique boundary group
        u32 cum = cumAbove;
        int d = t * 8;
        for (int q = 7; q >= 0; --q) {
            if (cum + hv[q] >= need) { d = t * 8 + q; break; }
            cum += hv[q];
        }
        bc[0] = (u32)d;
        bc[1] = need - cum;
    }
    __syncthreads();
}

// ---------------- the persistent mega-kernel: whole pipeline, 5 grid barriers ----------
__global__ __launch_bounds__(256, 4) void mega(
    const float* __restrict__ scores, const float* __restrict__ rois,
    const float* __restrict__ reg,
    u32* __restrict__ hist1, u32* __restrict__ hist2,
    u32* __restrict__ gcount, u32* __restrict__ bar, u64* __restrict__ gbuf,
    float* __restrict__ tbox, float* __restrict__ tobox,
    float* __restrict__ tscore, float* __restrict__ tcls, u32* __restrict__ tvalid,
    u64* __restrict__ maskT, float* __restrict__ out) {
    __shared__ union {
        u32 h[2048];
        u64 k[2048];
        float jb[4][64][4];
    } sm;
    __shared__ u32 suf[256];
    __shared__ u32 bc[2];
    __shared__ u32 lcnt, lbase;
    __shared__ u64 skept[NW];

    const int b = blockIdx.y, bx = blockIdx.x, t = threadIdx.x;
    const float4* sp = (const float4*)(scores + (size_t)b * NC);
    const int nvec = NC / 4;

    // ---- P1: 11-bit top histogram -> hist1[b] ----
    for (int i = t; i < 2048; i += 256) sm.h[i] = 0;
    __syncthreads();
    for (int v = bx * 256 + t; v < nvec; v += GB * 256) {
        float4 s4 = sp[v];
        float ss[4] = {s4.x, s4.y, s4.z, s4.w};
        #pragma unroll
        for (int q = 0; q < 4; ++q) {
            float s = ss[q] > SCORE_THR ? ss[q] : -1.0f;
            atomicAdd(&sm.h[mapf(s) >> 21], 1u);
        }
    }
    __syncthreads();
    for (int i = t; i < 2048; i += 256)
        if (sm.h[i]) atomicAdd(&hist1[b * 2048 + i], sm.h[i]);
    gbar(bar, 0);

    // ---- P2: (d0, rem); 11-bit second histogram -> hist2[b] ----
    sel_digit(hist1 + b * 2048, (u32)KK, suf, bc);
    u32 d0 = bc[0], rem = bc[1];
    for (int i = t; i < 2048; i += 256) sm.h[i] = 0;
    __syncthreads();
    for (int v = bx * 256 + t; v < nvec; v += GB * 256) {
        float4 s4 = sp[v];
        float ss[4] = {s4.x, s4.y, s4.z, s4.w};
        #pragma unroll
        for (int q = 0; q < 4; ++q) {
            float s = ss[q] > SCORE_THR ? ss[q] : -1.0f;
            u32 m = mapf(s);
            if ((m >> 21) == d0) atomicAdd(&sm.h[(m >> 10) & 0x7FFu], 1u);
        }
    }
    __syncthreads();
    for (int i = t; i < 2048; i += 256)
        if (sm.h[i]) atomicAdd(&hist2[b * 2048 + i], sm.h[i]);
    gbar(bar, 1);

    // ---- P3: 22-bit threshold; gather superset (block-aggregated) ----
    sel_digit(hist2 + b * 2048, rem, suf, bc);
    u32 thr = ((d0 << 11) | bc[0]) << 10;
    if (t == 0) lcnt = 0;
    __syncthreads();
    for (int v = bx * 256 + t; v < nvec; v += GB * 256) {
        float4 s4 = sp[v];
        float ss[4] = {s4.x, s4.y, s4.z, s4.w};
        #pragma unroll
        for (int q = 0; q < 4; ++q) {
            float s = ss[q] > SCORE_THR ? ss[q] : -1.0f;
            u32 m = mapf(s);
            if (m >= thr) {
                u32 p = atomicAdd(&lcnt, 1u);
                if (p < CAP) {
                    u32 idx = (u32)(v * 4 + q);
                    sm.k[p] = ((u64)m << 32) | (u64)(MAXIDX - idx);
                }
            }
        }
    }
    __syncthreads();
    if (t == 0) {
        u32 c = lcnt; if (c > CAP) c = CAP;
        lcnt = c;
        lbase = atomicAdd(&gcount[b], c);
    }
    __syncthreads();
    {
        u32 c = lcnt, base = lbase;
        for (u32 i = t; i < c; i += 256) {
            u32 p = base + i;
            if (p < CAP) gbuf[(size_t)b * CAP + p] = sm.k[i];
        }
    }
    gbar(bar, 2);

    // ---- P4: blocks bx==0 sort (bitonic desc) + decode top-K ----
    if (bx == 0) {
        u32 cnt = gcount[b]; if (cnt > CAP) cnt = CAP;
        for (int i = t; i < CAP; i += 256)
            sm.k[i] = (i < (int)cnt) ? gbuf[(size_t)b * CAP + i] : 0ull;
        __syncthreads();
        for (int k = 2; k <= CAP; k <<= 1) {
            for (int j = k >> 1; j > 0; j >>= 1) {
                for (int i = t; i < CAP; i += 256) {
                    int ixj = i ^ j;
                    if (ixj > i) {
                        u64 a = sm.k[i], c = sm.k[ixj];
                        bool desc = ((i & k) == 0);
                        if ((a < c) == desc) { sm.k[i] = c; sm.k[ixj] = a; }
                    }
                }
                __syncthreads();
            }
        }
        for (int kk = t; kk < KK; kk += 256) {
            u64 key = sm.k[kk];
            float score, cf, box0, box1, box2, box3;
            u32 vld;
            if (kk < (int)cnt) {
                u32 m = (u32)(key >> 32);
                u32 idx = (u32)MAXIDX - (u32)(key & 0xFFFFFFFFu);
                score = unmapf(m);
                vld = (score > SCORE_THR) ? 1u : 0u;
                int n = idx / CC, c = idx % CC;
                cf = (float)(c + 1);
                const float* r = rois + ((size_t)b * NN + n) * 4;
                const float* d = reg  + ((size_t)b * NN + n) * 4;
                float x1 = r[0], y1 = r[1], x2 = r[2], y2 = r[3];
                float w = x2 - x1, h = y2 - y1;
                float cx = x1 + 0.5f * w, cy = y1 + 0.5f * h;
                float dx = d[0], dy = d[1];
                float dw = fminf(fmaxf(d[2], -MAX_RATIO), MAX_RATIO);
                float dh = fminf(fmaxf(d[3], -MAX_RATIO), MAX_RATIO);
                float pw = w * expf(dw), ph = h * expf(dh);
                float pcx = cx + dx * w, pcy = cy + dy * h;
                box0 = pcx - 0.5f * pw; box1 = pcy - 0.5f * ph;
                box2 = pcx + 0.5f * pw; box3 = pcy + 0.5f * ph;
            } else {
                score = -1.0f; cf = 0.0f; vld = 0u; box0 = box1 = box2 = box3 = 0.0f;
            }
            size_t o = (size_t)b * KK + kk;
            tscore[o] = score; tcls[o] = cf; tvalid[o] = vld;
            float off = cf * CLS_OFF;
            tbox[o*4+0] = box0; tbox[o*4+1] = box1; tbox[o*4+2] = box2; tbox[o*4+3] = box3;
            tobox[o*4+0] = box0 + off; tobox[o*4+1] = box1 + off;
            tobox[o*4+2] = box2 + off; tobox[o*4+3] = box3 + off;
        }
    }
    gbar(bar, 3);

    // ---- P5: IoU bitmask, lower-triangle tiles; 4 tiles per block ----
    {
        int g = t >> 6, lane = t & 63;
        int T = bx * 4 + g;
        if (T < NTILE) {
            int ib = (int)((sqrtf(8.0f * (float)T + 1.0f) - 1.0f) * 0.5f);
            while ((ib + 1) * (ib + 2) / 2 <= T) ++ib;
            while (ib * (ib + 1) / 2 > T) --ib;
            int jbk = T - ib * (ib + 1) / 2;
            int j0 = jbk * 64;
            int jg = j0 + lane;
            float* jb = sm.jb[g][lane];
            if (jg < KK) {
                const float* p = tobox + ((size_t)b * KK + jg) * 4;
                jb[0] = p[0]; jb[1] = p[1]; jb[2] = p[2]; jb[3] = p[3];
            } else {
                jb[0] = 0; jb[1] = 0; jb[2] = 0; jb[3] = 0;
            }
            int i = ib * 64 + lane;
            if (i < KK) {
                const float* p = tobox + ((size_t)b * KK + i) * 4;
                float x1 = p[0], y1 = p[1], x2 = p[2], y2 = p[3];
                float ai = (x2 - x1) * (y2 - y1);
                u64 bits = 0;
                int jmax = min(64, KK - j0);
                for (int jj = 0; jj < jmax; ++jj) {
                    const float* q = sm.jb[g][jj];
                    float bx1 = q[0], by1 = q[1], bx2 = q[2], by2 = q[3];
                    float aj = (bx2 - bx1) * (by2 - by1);
                    float iw = fmaxf(fminf(x2, bx2) - fmaxf(x1, bx1), 0.0f);
                    float ih = fmaxf(fminf(y2, by2) - fmaxf(y1, by1), 0.0f);
                    float inter = iw * ih;
                    float iou = inter / (ai + aj - inter + 1e-9f);
                    if (iou > NMS_THR) bits |= (1ull << jj);
                }
                maskT[((size_t)b * NW + jbk) * KK + i] = bits;
            }
        }
    }
    gbar(bar, 4);

    // ---- P6: blocks bx==0: ballot fixed-point NMS + masked output ----
    if (bx != 0) return;
    if (t < 64) {
        int lane = t;
        const u64* mT = maskT + (size_t)b * NW * KK;
        u64 keptW[NW];
        #pragma unroll
        for (int W = 0; W < NW; ++W) {
            int i = W * 64 + lane;
            bool inr = (i < KK);
            u64 row[NW];
            #pragma unroll
            for (int w = 0; w <= W; ++w)
                row[w] = inr ? mT[(size_t)w * KK + i] : 0ull;
            bool valid = inr && (tvalid[(size_t)b * KK + i] != 0u);
            u64 ext = 0;
            #pragma unroll
            for (int w = 0; w < W; ++w) ext |= keptW[w] & row[w];
            bool cand = valid && (ext == 0ull);
            u64 m_self = row[W] & ((1ull << lane) - 1ull);
            u64 kept = __ballot(cand);
            while (true) {
                u64 k2 = __ballot(cand && ((kept & m_self) == 0ull));
                if (k2 == kept) break;
                kept = k2;
            }
            keptW[W] = kept;
            if (lane == 0) skept[W] = kept;
        }
    }
    __syncthreads();
    for (int kk = t; kk < KK; kk += 256) {
        size_t o = (size_t)b * KK + kk;
        float kf = (float)((skept[kk >> 6] >> (kk & 63)) & 1ull);
        float* op = out + o * 7;
        op[0] = tbox[o*4+0] * kf; op[1] = tbox[o*4+1] * kf;
        op[2] = tbox[o*4+2] * kf; op[3] = tbox[o*4+3] * kf;
        op[4] = tscore[o] * kf;   op[5] = tcls[o] * kf;   op[6] = kf;
    }
}

extern "C" void kernel_launch(void* const* d_in, const int* in_sizes, int n_in,
                              void* d_out, int out_size, void* d_ws, size_t ws_size,
                              hipStream_t stream) {
    const float* rois   = (const float*)d_in[0];   // (B,N,4)
    const float* scores = (const float*)d_in[1];   // (B*N,C,1,1) == (B, N*C)
    const float* reg    = (const float*)d_in[2];   // (B*N,4,1,1)
    float* out = (float*)d_out;

    char* ws = (char*)d_ws;
    u32* hist1  = (u32*)(ws + WS_HIST1);
    u32* hist2  = (u32*)(ws + WS_HIST2);
    u32* gcount = (u32*)(ws + WS_GCOUNT);
    u32* bar    = (u32*)(ws + WS_BAR);
    u64* gbuf   = (u64*)(ws + WS_GBUF);
    float* tbox   = (float*)(ws + WS_TBOX);
    float* tobox  = (float*)(ws + WS_TOBOX);
    float* tscore = (float*)(ws + WS_TSCORE);
    float* tcls   = (float*)(ws + WS_TCLS);
    u32*   tvalid = (u32*)(ws + WS_TVALID);
    u64*   maskT  = (u64*)(ws + WS_MASK);

    init_ws<<<(WS_CTRL_END / 16 + 255) / 256, 256, 0, stream>>>((uint4*)ws);

    mega<<<dim3(GB, BB), 256, 0, stream>>>(scores, rois, reg,
                                           hist1, hist2, gcount, bar, gbuf,
                                           tbox, tobox, tscore, tcls, tvalid,
                                           maskT, out);
}

// Round 8
// 139.811 us; speedup vs baseline: 4.0627x; 4.0627x over previous
//
#include <hip/hip_runtime.h>
#include <stdint.h>

typedef unsigned int u32;
typedef unsigned long long u64;

#define BB 8
#define NN 8192
#define CC 80
#define KK 1000
#define NC (NN*CC)            // 655360
#define MAXIDX (NC-1)
#define NMS_THR 0.5f
#define SCORE_THR 0.05f
#define MAX_RATIO 4.135166556742356f
#define CLS_OFF 10000.0f
#define CAP 2048
#define NW 16                 // u64 words per mask row
#define HGB 128               // blocks per batch, hist1 + stage
#define D4X 32                // blocks per batch, select/sort
#define D5X 34                // blocks per batch, iou/nms (34*4 = 136 tiles)
#define NTILE 136
#define LBUF 1024             // per-block staging buffer (u64)
#define GBUFCAP 98304         // per-batch superset capacity (u64)

#define SC_AGENT __HIP_MEMORY_SCOPE_AGENT

// ---- workspace layout (bytes) ----
#define WS_HIST1   0          // 8*2048*4 = 65536
#define WS_HIST2   65536      // 65536
#define WS_GCOUNT  131072     // 32
#define WS_GCOUNT2 131104     // 32
#define WS_TICK4   131136     // 32
#define WS_TICK5   131168     // 32
#define WS_CTRL_END 131200    // zeroed by init_ws (= 16*8200)
#define WS_GBUF    131200     // 8*98304*8 = 6291456 -> 6422656
#define WS_GBUF2   6422656    // 8*2048*8 = 131072 -> 6553728
#define WS_TBOX    6553728    // 128000
#define WS_TOBOX   6681728    // 128000
#define WS_TSCORE  6809728    // 32000
#define WS_TCLS    6841728    // 32000
#define WS_TVALID  6873728    // 32000
#define WS_MASK    6905728    // 8*16*1000*8 = 1024000 -> 7929728

__device__ __forceinline__ u32 mapf(float f) {
    u32 u = __float_as_uint(f);
    return (u & 0x80000000u) ? ~u : (u | 0x80000000u);
}
__device__ __forceinline__ float unmapf(u32 m) {
    u32 u = (m & 0x80000000u) ? (m ^ 0x80000000u) : ~m;
    return __uint_as_float(u);
}

// ---------------- init: zero control region ----------------
__global__ __launch_bounds__(256) void init_ws(uint4* __restrict__ p) {
    int i = blockIdx.x * blockDim.x + threadIdx.x;
    if (i < (WS_CTRL_END / 16)) p[i] = make_uint4(0u, 0u, 0u, 0u);
}

// digit-select from a finalized 2048-bin histogram (descending). blockDim=256.
// bc[0]=digit, bc[1]=remaining need inside that digit.
__device__ __forceinline__ void sel_digit(const u32* __restrict__ h, u32 need,
                                          u32* suf, u32* bc) {
    int t = threadIdx.x;
    u32 hv[8];
    u32 s = 0;
    #pragma unroll
    for (int q = 0; q < 8; ++q) { hv[q] = h[t * 8 + q]; s += hv[q]; }
    u32 grp = s;
    suf[t] = s;
    __syncthreads();
    #pragma unroll
    for (int off = 1; off < 256; off <<= 1) {
        u32 v = (t + off < 256) ? suf[t + off] : 0u;
        __syncthreads();
        suf[t] += v;
        __syncthreads();
    }
    u32 cumAbove = suf[t] - grp;
    if (cumAbove < need && suf[t] >= need) {     // unique boundary group
        u32 cum = cumAbove;
        int d = t * 8;
        for (int q = 7; q >= 0; --q) {
            if (cum + hv[q] >= need) { d = t * 8 + q; break; }
            cum += hv[q];
        }
        bc[0] = (u32)d;
        bc[1] = need - cum;
    }
    __syncthreads();
}

// ---------------- D2: 11-bit top histogram ----------------
__global__ __launch_bounds__(256) void hist1_pass(const float* __restrict__ scores,
                                                  u32* __restrict__ hist1) {
    __shared__ u32 lh[2048];
    int b = blockIdx.y;
    for (int i = threadIdx.x; i < 2048; i += 256) lh[i] = 0;
    __syncthreads();
    const float4* sp = (const float4*)(scores + (size_t)b * NC);
    int nvec = NC / 4;
    for (int v = blockIdx.x * 256 + threadIdx.x; v < nvec; v += HGB * 256) {
        float4 s4 = sp[v];
        float ss[4] = {s4.x, s4.y, s4.z, s4.w};
        #pragma unroll
        for (int q = 0; q < 4; ++q) {
            float s = ss[q] > SCORE_THR ? ss[q] : -1.0f;
            atomicAdd(&lh[mapf(s) >> 21], 1u);
        }
    }
    __syncthreads();
    for (int i = threadIdx.x; i < 2048; i += 256)
        if (lh[i]) atomicAdd(&hist1[b * 2048 + i], lh[i]);
}

// ---------------- D3: stage d0-superset + build hist2 (bits 20..10 of d0-items) ------
__global__ __launch_bounds__(256) void stage_pass(
    const float* __restrict__ scores, const u32* __restrict__ hist1,
    u32* __restrict__ hist2, u64* __restrict__ gbuf, u32* __restrict__ gcount) {
    __shared__ u64 buf[LBUF];
    __shared__ u32 h2[2048];
    __shared__ u32 suf[256];
    __shared__ u32 bc[2];
    __shared__ u32 lcnt, lbase;
    int b = blockIdx.y, bx = blockIdx.x, t = threadIdx.x;
    for (int i = t; i < 2048; i += 256) h2[i] = 0;
    if (t == 0) lcnt = 0;
    sel_digit(hist1 + b * 2048, (u32)KK, suf, bc);   // syncs internally
    u32 d0 = bc[0];
    const float4* sp = (const float4*)(scores + (size_t)b * NC);
    int nvec = NC / 4;
    for (int v = bx * 256 + t; v < nvec; v += HGB * 256) {
        float4 s4 = sp[v];
        float ss[4] = {s4.x, s4.y, s4.z, s4.w};
        #pragma unroll
        for (int q = 0; q < 4; ++q) {
            float s = ss[q] > SCORE_THR ? ss[q] : -1.0f;
            u32 m = mapf(s);
            u32 top = m >> 21;
            if (top >= d0) {
                u32 p = atomicAdd(&lcnt, 1u);
                if (p < LBUF) {
                    u32 idx = (u32)(v * 4 + q);
                    buf[p] = ((u64)m << 32) | (u64)(MAXIDX - idx);
                }
                if (top == d0) atomicAdd(&h2[(m >> 10) & 0x7FFu], 1u);
            }
        }
    }
    __syncthreads();
    for (int i = t; i < 2048; i += 256)
        if (h2[i]) atomicAdd(&hist2[b * 2048 + i], h2[i]);
    if (t == 0) {
        u32 c = lcnt; if (c > LBUF) c = LBUF;
        lcnt = c;
        lbase = atomicAdd(&gcount[b], c);
    }
    __syncthreads();
    u32 c = lcnt, base = lbase;
    for (u32 i = t; i < c; i += 256) {
        u32 p = base + i;
        if (p < GBUFCAP) gbuf[(size_t)b * GBUFCAP + p] = buf[i];
    }
}

// ---------------- D4: exact 22-bit filter -> ticket-last block sorts + decodes -------
__global__ __launch_bounds__(256) void select_sort_decode(
    const u64* __restrict__ gbuf, const u32* __restrict__ gcount,
    const u32* __restrict__ hist1, const u32* __restrict__ hist2,
    u64* __restrict__ gbuf2, u32* __restrict__ gcount2, u32* __restrict__ tick,
    const float* __restrict__ rois, const float* __restrict__ reg,
    float* __restrict__ tbox, float* __restrict__ tobox,
    float* __restrict__ tscore, float* __restrict__ tcls, u32* __restrict__ tvalid) {
    __shared__ u64 kbuf[CAP];
    __shared__ u64 buf2[256];
    __shared__ u32 suf[256];
    __shared__ u32 bc[2];
    __shared__ u32 l2cnt, l2base;
    __shared__ int islast;
    int b = blockIdx.y, bx = blockIdx.x, t = threadIdx.x;
    if (t == 0) l2cnt = 0;
    sel_digit(hist1 + b * 2048, (u32)KK, suf, bc);
    u32 d0 = bc[0], rem = bc[1];
    __syncthreads();
    sel_digit(hist2 + b * 2048, rem, suf, bc);
    u32 thr = ((d0 << 11) | bc[0]) << 10;
    u32 cnt = gcount[b]; if (cnt > GBUFCAP) cnt = GBUFCAP;
    u32 chunk = (cnt + D4X - 1) / D4X;
    u32 lo = bx * chunk, hi = lo + chunk; if (hi > cnt) hi = cnt;
    const u64* gb = gbuf + (size_t)b * GBUFCAP;
    for (u32 i = lo + t; i < hi; i += 256) {
        u64 key = gb[i];
        if ((u32)(key >> 32) >= thr) {
            u32 p = atomicAdd(&l2cnt, 1u);
            if (p < 256u) buf2[p] = key;
        }
    }
    __syncthreads();
    if (t == 0) {
        u32 c = l2cnt; if (c > 256u) c = 256u;
        l2cnt = c;
        l2base = atomicAdd(&gcount2[b], c);
    }
    __syncthreads();
    {
        u32 c = l2cnt, base = l2base;
        if (t < c) {
            u32 p = base + t;
            if (p < CAP)
                __hip_atomic_store(&gbuf2[(size_t)b * CAP + p], buf2[t],
                                   __ATOMIC_RELAXED, SC_AGENT);
        }
    }
    __syncthreads();
    if (t == 0) {
        u32 tk = __hip_atomic_fetch_add(&tick[b], 1u, __ATOMIC_ACQ_REL, SC_AGENT);
        islast = (tk == (u32)(D4X - 1)) ? 1 : 0;
    }
    __syncthreads();
    if (!islast) return;

    // ---- last block: load candidates, bitonic sort (desc), decode top-K ----
    u32 cnt2 = __hip_atomic_load(&gcount2[b], __ATOMIC_RELAXED, SC_AGENT);
    if (cnt2 > CAP) cnt2 = CAP;
    for (int i = t; i < CAP; i += 256)
        kbuf[i] = (i < (int)cnt2)
            ? __hip_atomic_load(&gbuf2[(size_t)b * CAP + i], __ATOMIC_RELAXED, SC_AGENT)
            : 0ull;
    __syncthreads();
    for (int k = 2; k <= CAP; k <<= 1) {
        for (int j = k >> 1; j > 0; j >>= 1) {
            for (int i = t; i < CAP; i += 256) {
                int ixj = i ^ j;
                if (ixj > i) {
                    u64 a = kbuf[i], c = kbuf[ixj];
                    bool desc = ((i & k) == 0);
                    if ((a < c) == desc) { kbuf[i] = c; kbuf[ixj] = a; }
                }
            }
            __syncthreads();
        }
    }
    for (int kk = t; kk < KK; kk += 256) {
        u64 key = kbuf[kk];
        float score, cf, box0, box1, box2, box3;
        u32 vld;
        if (kk < (int)cnt2) {
            u32 m = (u32)(key >> 32);
            u32 idx = (u32)MAXIDX - (u32)(key & 0xFFFFFFFFu);
            score = unmapf(m);
            vld = (score > SCORE_THR) ? 1u : 0u;
            int n = idx / CC, c = idx % CC;
            cf = (float)(c + 1);
            const float* r = rois + ((size_t)b * NN + n) * 4;
            const float* d = reg  + ((size_t)b * NN + n) * 4;
            float x1 = r[0], y1 = r[1], x2 = r[2], y2 = r[3];
            float w = x2 - x1, h = y2 - y1;
            float cx = x1 + 0.5f * w, cy = y1 + 0.5f * h;
            float dx = d[0], dy = d[1];
            float dw = fminf(fmaxf(d[2], -MAX_RATIO), MAX_RATIO);
            float dh = fminf(fmaxf(d[3], -MAX_RATIO), MAX_RATIO);
            float pw = w * expf(dw), ph = h * expf(dh);
            float pcx = cx + dx * w, pcy = cy + dy * h;
            box0 = pcx - 0.5f * pw; box1 = pcy - 0.5f * ph;
            box2 = pcx + 0.5f * pw; box3 = pcy + 0.5f * ph;
        } else {
            score = -1.0f; cf = 0.0f; vld = 0u; box0 = box1 = box2 = box3 = 0.0f;
        }
        size_t o = (size_t)b * KK + kk;
        tscore[o] = score; tcls[o] = cf; tvalid[o] = vld;
        float off = cf * CLS_OFF;
        tbox[o*4+0] = box0; tbox[o*4+1] = box1; tbox[o*4+2] = box2; tbox[o*4+3] = box3;
        tobox[o*4+0] = box0 + off; tobox[o*4+1] = box1 + off;
        tobox[o*4+2] = box2 + off; tobox[o*4+3] = box3 + off;
    }
}

// ---------------- D5: IoU tiles (lower triangle) -> ticket-last block does NMS -------
__global__ __launch_bounds__(256) void iou_nms(
    const float* __restrict__ tobox, const u32* __restrict__ tvalid,
    const float* __restrict__ tbox, const float* __restrict__ tscore,
    const float* __restrict__ tcls,
    u64* __restrict__ maskT, u32* __restrict__ tick, float* __restrict__ out) {
    __shared__ float jbs[4][64][4];
    __shared__ u64 skept[NW];
    __shared__ int islast;
    int b = blockIdx.y, bx = blockIdx.x, t = threadIdx.x;
    int g = t >> 6, lane = t & 63;
    int T = bx * 4 + g;                      // 0..135, all valid (34*4 = 136)
    {
        int ib = (int)((sqrtf(8.0f * (float)T + 1.0f) - 1.0f) * 0.5f);
        while ((ib + 1) * (ib + 2) / 2 <= T) ++ib;
        while (ib * (ib + 1) / 2 > T) --ib;
        int jbk = T - ib * (ib + 1) / 2;
        int j0 = jbk * 64;
        int jg = j0 + lane;
        float* jb = jbs[g][lane];
        if (jg < KK) {
            const float* p = tobox + ((size_t)b * KK + jg) * 4;
            jb[0] = p[0]; jb[1] = p[1]; jb[2] = p[2]; jb[3] = p[3];
        } else {
            jb[0] = 0; jb[1] = 0; jb[2] = 0; jb[3] = 0;
        }
        // group-local sync not available; lanes within 64-lane group are one wave,
        // and jbs[g] is written/read only by that wave -> safe without barrier.
        int i = ib * 64 + lane;
        if (i < KK) {
            const float* p = tobox + ((size_t)b * KK + i) * 4;
            float x1 = p[0], y1 = p[1], x2 = p[2], y2 = p[3];
            float ai = (x2 - x1) * (y2 - y1);
            u64 bits = 0;
            int jmax = min(64, KK - j0);
            for (int jj = 0; jj < jmax; ++jj) {
                const float* q = jbs[g][jj];
                float bx1 = q[0], by1 = q[1], bx2 = q[2], by2 = q[3];
                float aj = (bx2 - bx1) * (by2 - by1);
                float iw = fmaxf(fminf(x2, bx2) - fmaxf(x1, bx1), 0.0f);
                float ih = fmaxf(fminf(y2, by2) - fmaxf(y1, by1), 0.0f);
                float inter = iw * ih;
                float iou = inter / (ai + aj - inter + 1e-9f);
                if (iou > NMS_THR) bits |= (1ull << jj);
            }
            __hip_atomic_store(&maskT[((size_t)b * NW + jbk) * KK + i], bits,
                               __ATOMIC_RELAXED, SC_AGENT);
        }
    }
    __syncthreads();
    if (t == 0) {
        u32 tk = __hip_atomic_fetch_add(&tick[b], 1u, __ATOMIC_ACQ_REL, SC_AGENT);
        islast = (tk == (u32)(D5X - 1)) ? 1 : 0;
    }
    __syncthreads();
    if (!islast) return;

    // ---- last block: ballot fixed-point NMS from device-coherent mask ----
    if (t < 64) {
        int ln = t;
        const u64* mT = maskT + (size_t)b * NW * KK;
        u64 keptW[NW];
        #pragma unroll
        for (int W = 0; W < NW; ++W) {
            int i = W * 64 + ln;
            bool inr = (i < KK);
            u64 row[NW];
            #pragma unroll
            for (int w = 0; w <= W; ++w)
                row[w] = inr ? __hip_atomic_load(&mT[(size_t)w * KK + i],
                                                 __ATOMIC_RELAXED, SC_AGENT) : 0ull;
            bool valid = inr && (tvalid[(size_t)b * KK + i] != 0u);
            u64 ext = 0;
            #pragma unroll
            for (int w = 0; w < W; ++w) ext |= keptW[w] & row[w];
            bool cand = valid && (ext == 0ull);
            u64 m_self = row[W] & ((1ull << ln) - 1ull);
            u64 kept = __ballot(cand);
            while (true) {
                u64 k2 = __ballot(cand && ((kept & m_self) == 0ull));
                if (k2 == kept) break;
                kept = k2;
            }
            keptW[W] = kept;
            if (ln == 0) skept[W] = kept;
        }
    }
    __syncthreads();
    for (int kk = t; kk < KK; kk += 256) {
        size_t o = (size_t)b * KK + kk;
        float kf = (float)((skept[kk >> 6] >> (kk & 63)) & 1ull);
        float* op = out + o * 7;
        op[0] = tbox[o*4+0] * kf; op[1] = tbox[o*4+1] * kf;
        op[2] = tbox[o*4+2] * kf; op[3] = tbox[o*4+3] * kf;
        op[4] = tscore[o] * kf;   op[5] = tcls[o] * kf;   op[6] = kf;
    }
}

extern "C" void kernel_launch(void* const* d_in, const int* in_sizes, int n_in,
                              void* d_out, int out_size, void* d_ws, size_t ws_size,
                              hipStream_t stream) {
    const float* rois   = (const float*)d_in[0];   // (B,N,4)
    const float* scores = (const float*)d_in[1];   // (B*N,C,1,1) == (B, N*C)
    const float* reg    = (const float*)d_in[2];   // (B*N,4,1,1)
    float* out = (float*)d_out;

    char* ws = (char*)d_ws;
    u32* hist1   = (u32*)(ws + WS_HIST1);
    u32* hist2   = (u32*)(ws + WS_HIST2);
    u32* gcount  = (u32*)(ws + WS_GCOUNT);
    u32* gcount2 = (u32*)(ws + WS_GCOUNT2);
    u32* tick4   = (u32*)(ws + WS_TICK4);
    u32* tick5   = (u32*)(ws + WS_TICK5);
    u64* gbuf    = (u64*)(ws + WS_GBUF);
    u64* gbuf2   = (u64*)(ws + WS_GBUF2);
    float* tbox   = (float*)(ws + WS_TBOX);
    float* tobox  = (float*)(ws + WS_TOBOX);
    float* tscore = (float*)(ws + WS_TSCORE);
    float* tcls   = (float*)(ws + WS_TCLS);
    u32*   tvalid = (u32*)(ws + WS_TVALID);
    u64*   maskT  = (u64*)(ws + WS_MASK);

    init_ws<<<(WS_CTRL_END / 16 + 255) / 256, 256, 0, stream>>>((uint4*)ws);

    hist1_pass<<<dim3(HGB, BB), 256, 0, stream>>>(scores, hist1);

    stage_pass<<<dim3(HGB, BB), 256, 0, stream>>>(scores, hist1, hist2, gbuf, gcount);

    select_sort_decode<<<dim3(D4X, BB), 256, 0, stream>>>(
        gbuf, gcount, hist1, hist2, gbuf2, gcount2, tick4,
        rois, reg, tbox, tobox, tscore, tcls, tvalid);

    iou_nms<<<dim3(D5X, BB), 256, 0, stream>>>(
        tobox, tvalid, tbox, tscore, tcls, maskT, tick5, out);
}